// Round 5
// baseline (1353.552 us; speedup 1.0000x reference)
//
#include <hip/hip_runtime.h>
#include <hip/hip_bf16.h>

#define NN 8192
#define KF 256
#define KD 512
#define CK 32

typedef unsigned int uint32;
typedef unsigned short ushort16;

static __device__ __forceinline__ float bf2f(ushort16 u) {
    union { uint32 i; float f; } v; v.i = ((uint32)u) << 16; return v.f;
}
static __device__ __forceinline__ ushort16 f2bf(float f) {
    __hip_bfloat16 h = __float2bfloat16(f);  // RNE
    union { __hip_bfloat16 h; ushort16 u; } v; v.h = h; return v.u;
}

// ---------------- K-1: detect input dtype ----------------
__global__ void detect_kernel(const uint32* __restrict__ rawA, int* __restrict__ flag) {
    __shared__ int s_top2, s_nz;
    if (threadIdx.x == 0) { s_top2 = 0; s_nz = 0; }
    __syncthreads();
    int top2 = 0, nz = 0;
    for (int i = threadIdx.x; i < 4096; i += 256) {
        uint32 lo = rawA[i] & 0xFFFFu;
        if (lo & 0xC000u) top2 = 1;
        if (lo) nz = 1;
    }
    if (top2) atomicOr(&s_top2, 1);
    if (nz) atomicOr(&s_nz, 1);
    __syncthreads();
    if (threadIdx.x == 0) {
        int f;
        if (s_top2) f = 1;        // true fp32
        else if (s_nz) f = 0;     // bf16 storage
        else f = 1;               // fp32 holding bf16-rounded values
        *flag = f;
    }
}

// ---------------- K0: zero accumulators ----------------
__global__ void init_kernel(double* acc, double* gstats) {
    int i = blockIdx.x * 256 + threadIdx.x;
    if (i < 4 * NN) acc[i] = 0.0;
    if (i < 2) gstats[i] = 0.0;
}

// ---------------- K1: top-32 mask + build X = [Ac | As] (fp32) + sq ----------------
__global__ void prep_kernel(const void* __restrict__ P_, const void* __restrict__ A_,
                            const int* __restrict__ flag,
                            float* __restrict__ X, float* __restrict__ sq) {
    int f = *flag;
    int row = blockIdx.x * 4 + (threadIdx.x >> 6);
    int lane = threadIdx.x & 63;
    if (row >= NN) return;
    float a[4], p[4];
    bool sel[4] = {false, false, false, false};
    if (f) {
        const float* Ar = (const float*)A_ + (size_t)row * KF;
        const float* Pr = (const float*)P_ + (size_t)row * KF;
#pragma unroll
        for (int j = 0; j < 4; j++) {
            int k = lane + 64 * j;
            a[j] = Ar[k];
            p[j] = Pr[k];
        }
    } else {
        const __hip_bfloat16* Ar = (const __hip_bfloat16*)A_ + (size_t)row * KF;
        const __hip_bfloat16* Pr = (const __hip_bfloat16*)P_ + (size_t)row * KF;
#pragma unroll
        for (int j = 0; j < 4; j++) {
            int k = lane + 64 * j;
            a[j] = __bfloat162float(Ar[k]);
            p[j] = __bfloat162float(Pr[k]);
        }
    }
    for (int it = 0; it < CK; ++it) {
        float bv = -1.0f; int bi = KF;
#pragma unroll
        for (int j = 0; j < 4; j++) {
            int k = lane + 64 * j;
            if (!sel[j] && (a[j] > bv || (a[j] == bv && k < bi))) { bv = a[j]; bi = k; }
        }
        for (int off = 32; off > 0; off >>= 1) {
            float ov = __shfl_xor(bv, off);
            int   oi = __shfl_xor(bi, off);
            if (ov > bv || (ov == bv && oi < bi)) { bv = ov; bi = oi; }
        }
        if ((bi & 63) == lane) sel[bi >> 6] = true;
    }
    double sq_part = 0.0;
    float* Xr = X + (size_t)row * KD;
#pragma unroll
    for (int j = 0; j < 4; j++) {
        int k = lane + 64 * j;
        float c = 0.0f, s = 0.0f;
        if (sel[j]) {
            c = a[j] * cosf(p[j]);
            s = a[j] * sinf(p[j]);
            sq_part += (double)a[j] * (double)a[j];
        }
        Xr[k] = c;
        Xr[KF + k] = s;
    }
    for (int off = 32; off > 0; off >>= 1) sq_part += __shfl_xor(sq_part, off);
    if (lane == 0) sq[row] = (float)sq_part;
}

// ---------------- K2: symmetric fp32 GEMM, 128x128 tile, 128 thr, TM8xTN16 ----------------
#define BM 128
#define BN 128
#define BK 16
#define TM 8
#define TN 16
#define LDP 140   // swizzled physical row length: sw(127)=139 -> 140

static __device__ __forceinline__ int sw(int c) { return c + ((c >> 5) << 2); }

__global__ __launch_bounds__(128) __attribute__((amdgpu_waves_per_eu(2, 2)))
void gemm_kernel(const float* __restrict__ X, const float* __restrict__ sq,
                 void* __restrict__ outv, const int* __restrict__ flag,
                 double* __restrict__ rowsum, double* __restrict__ possum,
                 double* __restrict__ poscnt, double* __restrict__ negcnt) {
    int bx = blockIdx.x, by = blockIdx.y;
    if (bx < by) return;                    // upper-triangle tiles only
    __shared__ float As[BK][LDP];
    __shared__ float Bs[BK][LDP];
    int f = *flag;
    int tid = threadIdx.x;    // 0..127
    int tx = tid & 7;         // col group (TN=16)
    int ty = tid >> 3;        // row group (TM=8)
    int row0 = by * BM, col0 = bx * BN;

    float acc[TM][TN] = {};

    int slr = sw(tid);
    const float* Arow = X + (size_t)(row0 + tid) * KD;
    const float* Brow = X + (size_t)(col0 + tid) * KD;
    int sa0 = sw(ty * TM + 0), sa1 = sw(ty * TM + 4);
    int sb0 = sw(tx * TN + 0), sb1 = sw(tx * TN + 4);
    int sb2 = sw(tx * TN + 8), sb3 = sw(tx * TN + 12);

    for (int k0 = 0; k0 < KD; k0 += BK) {
        float4 a0 = *(const float4*)(Arow + k0 + 0);
        float4 a1 = *(const float4*)(Arow + k0 + 4);
        float4 a2 = *(const float4*)(Arow + k0 + 8);
        float4 a3 = *(const float4*)(Arow + k0 + 12);
        float4 b0 = *(const float4*)(Brow + k0 + 0);
        float4 b1 = *(const float4*)(Brow + k0 + 4);
        float4 b2 = *(const float4*)(Brow + k0 + 8);
        float4 b3 = *(const float4*)(Brow + k0 + 12);
        __syncthreads();
        As[0][slr] = a0.x;  As[1][slr] = a0.y;  As[2][slr] = a0.z;  As[3][slr] = a0.w;
        As[4][slr] = a1.x;  As[5][slr] = a1.y;  As[6][slr] = a1.z;  As[7][slr] = a1.w;
        As[8][slr] = a2.x;  As[9][slr] = a2.y;  As[10][slr] = a2.z; As[11][slr] = a2.w;
        As[12][slr] = a3.x; As[13][slr] = a3.y; As[14][slr] = a3.z; As[15][slr] = a3.w;
        Bs[0][slr] = b0.x;  Bs[1][slr] = b0.y;  Bs[2][slr] = b0.z;  Bs[3][slr] = b0.w;
        Bs[4][slr] = b1.x;  Bs[5][slr] = b1.y;  Bs[6][slr] = b1.z;  Bs[7][slr] = b1.w;
        Bs[8][slr] = b2.x;  Bs[9][slr] = b2.y;  Bs[10][slr] = b2.z; Bs[11][slr] = b2.w;
        Bs[12][slr] = b3.x; Bs[13][slr] = b3.y; Bs[14][slr] = b3.z; Bs[15][slr] = b3.w;
        __syncthreads();
#pragma unroll
        for (int k = 0; k < BK; k++) {
            float4 va0 = *(const float4*)&As[k][sa0];
            float4 va1 = *(const float4*)&As[k][sa1];
            float4 vb0 = *(const float4*)&Bs[k][sb0];
            float4 vb1 = *(const float4*)&Bs[k][sb1];
            float4 vb2 = *(const float4*)&Bs[k][sb2];
            float4 vb3 = *(const float4*)&Bs[k][sb3];
            float av[TM] = {va0.x, va0.y, va0.z, va0.w, va1.x, va1.y, va1.z, va1.w};
            float bv[TN] = {vb0.x, vb0.y, vb0.z, vb0.w, vb1.x, vb1.y, vb1.z, vb1.w,
                            vb2.x, vb2.y, vb2.z, vb2.w, vb3.x, vb3.y, vb3.z, vb3.w};
#pragma unroll
            for (int i = 0; i < TM; i++)
#pragma unroll
                for (int j = 0; j < TN; j++)
                    acc[i][j] = fmaf(av[i], bv[j], acc[i][j]);
        }
    }

    // ---- epilogue: R = num/denom in-place, direct store, row stats ----
    float sqi[TM], sqj[TN];
#pragma unroll
    for (int i = 0; i < TM; i++) sqi[i] = sq[row0 + ty * TM + i];
#pragma unroll
    for (int j = 0; j < TN; j++) sqj[j] = sq[col0 + tx * TN + j];

#pragma unroll
    for (int i = 0; i < TM; i++) {
        double rs_ = 0.0, ps_ = 0.0;
        float pc_ = 0.0f, nc_ = 0.0f;
#pragma unroll
        for (int j = 0; j < TN; j++) {
            float denom = sqrtf(sqi[i] * sqj[j] + 1e-10f);
            float r = acc[i][j] / denom;        // IEEE div, matches np
            acc[i][j] = r;
            rs_ += (double)r;
            if (r > 0.0f) { ps_ += (double)r; pc_ += 1.0f; }
            else if (r < 0.0f) { nc_ += 1.0f; }
        }
        size_t obase = (((size_t)(row0 + ty * TM + i)) << 13) + col0 + tx * TN;
        if (f) {
            float* O = (float*)outv;
            *(float4*)(O + obase + 0)  = make_float4(acc[i][0], acc[i][1], acc[i][2], acc[i][3]);
            *(float4*)(O + obase + 4)  = make_float4(acc[i][4], acc[i][5], acc[i][6], acc[i][7]);
            *(float4*)(O + obase + 8)  = make_float4(acc[i][8], acc[i][9], acc[i][10], acc[i][11]);
            *(float4*)(O + obase + 12) = make_float4(acc[i][12], acc[i][13], acc[i][14], acc[i][15]);
        } else {
            union { uint4 u; ushort16 s[8]; } pk0, pk1;
#pragma unroll
            for (int j = 0; j < 8; j++) pk0.s[j] = f2bf(acc[i][j]);
#pragma unroll
            for (int j = 0; j < 8; j++) pk1.s[j] = f2bf(acc[i][8 + j]);
            *(uint4*)((__hip_bfloat16*)outv + obase) = pk0.u;
            *(uint4*)((__hip_bfloat16*)outv + obase + 8) = pk1.u;
        }
        // reduce across the 8 tx-threads (consecutive lanes, same ty)
        for (int off = 1; off < 8; off <<= 1) {
            rs_ += __shfl_xor(rs_, off);
            ps_ += __shfl_xor(ps_, off);
            pc_ += __shfl_xor(pc_, off);
            nc_ += __shfl_xor(nc_, off);
        }
        if (tx == 0) {
            int gr = row0 + ty * TM + i;
            atomicAdd(&rowsum[gr], rs_);
            atomicAdd(&possum[gr], ps_);
            atomicAdd(&poscnt[gr], (double)pc_);
            atomicAdd(&negcnt[gr], (double)nc_);
        }
    }

    // ---- mirror tile (off-diagonal only): transposed store + column stats ----
    if (bx != by) {
        int l = tid & 63;
#pragma unroll
        for (int j = 0; j < TN; j++) {
            size_t mbase = (((size_t)(col0 + tx * TN + j)) << 13) + row0 + ty * TM;
            if (f) {
                float* O = (float*)outv;
                *(float4*)(O + mbase + 0) = make_float4(acc[0][j], acc[1][j], acc[2][j], acc[3][j]);
                *(float4*)(O + mbase + 4) = make_float4(acc[4][j], acc[5][j], acc[6][j], acc[7][j]);
            } else {
                union { uint4 u; ushort16 s[8]; } pk;
#pragma unroll
                for (int i = 0; i < 8; i++) pk.s[i] = f2bf(acc[i][j]);
                *(uint4*)((__hip_bfloat16*)outv + mbase) = pk.u;
            }
            double cs = 0.0, cp = 0.0;
            float cc = 0.0f, cn = 0.0f;
#pragma unroll
            for (int i = 0; i < TM; i++) {
                float r = acc[i][j];
                cs += (double)r;
                if (r > 0.0f) { cp += (double)r; cc += 1.0f; }
                else if (r < 0.0f) { cn += 1.0f; }
            }
            // reduce over the 8 ty-groups within this wave (lane bits 3,4,5)
            cs += __shfl_xor(cs, 8); cs += __shfl_xor(cs, 16); cs += __shfl_xor(cs, 32);
            cp += __shfl_xor(cp, 8); cp += __shfl_xor(cp, 16); cp += __shfl_xor(cp, 32);
            cc += __shfl_xor(cc, 8); cc += __shfl_xor(cc, 16); cc += __shfl_xor(cc, 32);
            cn += __shfl_xor(cn, 8); cn += __shfl_xor(cn, 16); cn += __shfl_xor(cn, 32);
            if (l < 8) {
                int gc = col0 + l * TN + j;    // tx == l for l < 8
                atomicAdd(&rowsum[gc], cs);
                atomicAdd(&possum[gc], cp);
                atomicAdd(&poscnt[gc], (double)cc);
                atomicAdd(&negcnt[gc], (double)cn);
            }
        }
    }
}

// ---------------- K3: per-row finalize + global positive stats ----------------
__global__ void rowfin_kernel(const double* __restrict__ rowsum, const double* __restrict__ possum,
                              const double* __restrict__ poscnt, const double* __restrict__ negcnt,
                              float* __restrict__ inv_rs, double* __restrict__ gstats) {
    __shared__ double sc[256], sn[256];
    int n = blockIdx.x * 256 + threadIdx.x;
    double rsumv = rowsum[n];
    double rs = rsumv + 1e-10;
    inv_rs[n] = (float)(1.0 / rs);
    double contrib, cnt;
    if (rs > 0.0) { contrib = possum[n] / rs; cnt = poscnt[n]; }
    else          { contrib = (rsumv - possum[n]) / rs; cnt = negcnt[n]; }
    sc[threadIdx.x] = contrib; sn[threadIdx.x] = cnt;
    __syncthreads();
    for (int s = 128; s > 0; s >>= 1) {
        if (threadIdx.x < s) { sc[threadIdx.x] += sc[threadIdx.x + s]; sn[threadIdx.x] += sn[threadIdx.x + s]; }
        __syncthreads();
    }
    if (threadIdx.x == 0) { atomicAdd(&gstats[0], sc[0]); atomicAdd(&gstats[1], sn[0]); }
}

// ---------------- K3b: tau ----------------
__global__ void tau_kernel(const double* __restrict__ gstats, float* __restrict__ tau) {
    double cnt = gstats[1];
    if (cnt < 1.0) cnt = 1.0;
    double mp = gstats[0] / cnt;
    tau[0] = (mp > 0.0) ? (float)mp : 1.0f;   // TAU_FACTOR = 1.0
}

// ---------------- K4: R' = R*inv_rs, threshold, in-place on d_out ----------------
__global__ void thresh_kernel(void* __restrict__ R_,
                              const float* __restrict__ inv_rs,
                              const float* __restrict__ tau_p,
                              const int* __restrict__ flag) {
    int f = *flag;
    float tau = *tau_p;
    size_t base = ((size_t)blockIdx.x * 256 + threadIdx.x) * 8;
    if (base >= (size_t)NN * NN) return;
    float inv = inv_rs[base >> 13];
    if (f) {
        float* R = (float*)R_;
        float4 v0 = *(float4*)(R + base);
        float4 v1 = *(float4*)(R + base + 4);
        float vv[8] = {v0.x, v0.y, v0.z, v0.w, v1.x, v1.y, v1.z, v1.w};
#pragma unroll
        for (int t = 0; t < 8; t++) {
            float val = vv[t] * inv;
            vv[t] = (val >= tau) ? val : 0.0f;
        }
        *(float4*)(R + base)     = make_float4(vv[0], vv[1], vv[2], vv[3]);
        *(float4*)(R + base + 4) = make_float4(vv[4], vv[5], vv[6], vv[7]);
    } else {
        __hip_bfloat16* R = (__hip_bfloat16*)R_;
        union { uint4 u; ushort16 s[8]; } in, out;
        in.u = *(const uint4*)(R + base);
#pragma unroll
        for (int t = 0; t < 8; t++) {
            float val = bf2f(in.s[t]) * inv;
            float r = (val >= tau) ? val : 0.0f;
            out.s[t] = f2bf(r);
        }
        *(uint4*)(R + base) = out.u;
    }
}

// ---------------- sentinel: ws too small -> unmistakable absmax signature ----------------
__global__ void sentinel_kernel(uint32* __restrict__ out, size_t n32) {
    size_t i = (size_t)blockIdx.x * 256 + threadIdx.x;
    if (i < n32) out[i] = 0x47C35000u;
}

extern "C" void kernel_launch(void* const* d_in, const int* in_sizes, int n_in,
                              void* d_out, int out_size, void* d_ws, size_t ws_size,
                              hipStream_t stream) {
    const void* P = d_in[0];
    const void* A = d_in[1];

    char* ws = (char*)d_ws;
    size_t off = 0;
    float* X = (float*)(ws + off);        off += (size_t)NN * KD * 4;   // 16 MB
    float* sqv = (float*)(ws + off);      off += (size_t)NN * 4;
    double* rowsum = (double*)(ws + off); off += (size_t)NN * 8;
    double* possum = (double*)(ws + off); off += (size_t)NN * 8;
    double* poscnt = (double*)(ws + off); off += (size_t)NN * 8;
    double* negcnt = (double*)(ws + off); off += (size_t)NN * 8;
    float* inv_rs = (float*)(ws + off);   off += (size_t)NN * 4;
    double* gstats = (double*)(ws + off); off += 16;
    float* tau = (float*)(ws + off);      off += 16;
    int* flag = (int*)(ws + off);         off += 16;

    if (ws_size < off) {
        size_t n32 = ((size_t)out_size * 2) / 4;
        sentinel_kernel<<<(int)((n32 + 255) / 256), 256, 0, stream>>>((uint32*)d_out, n32);
        return;
    }

    detect_kernel<<<1, 256, 0, stream>>>((const uint32*)A, flag);
    init_kernel<<<(4 * NN + 255) / 256, 256, 0, stream>>>(rowsum, gstats);
    prep_kernel<<<NN / 4, 256, 0, stream>>>(P, A, flag, X, sqv);
    dim3 ggrid(NN / BN, NN / BM);
    gemm_kernel<<<ggrid, 128, 0, stream>>>(X, sqv, d_out, flag, rowsum, possum, poscnt, negcnt);
    rowfin_kernel<<<NN / 256, 256, 0, stream>>>(rowsum, possum, poscnt, negcnt, inv_rs, gstats);
    tau_kernel<<<1, 1, 0, stream>>>(gstats, tau);
    thresh_kernel<<<(int)(((size_t)NN * NN / 8 + 255) / 256), 256, 0, stream>>>(d_out, inv_rs, tau, flag);
}

// Round 6
// 1066.617 us; speedup vs baseline: 1.2690x; 1.2690x over previous
//
#include <hip/hip_runtime.h>
#include <hip/hip_bf16.h>

#define NN 8192
#define KF 256
#define KD 512
#define CK 32
#define PACK 67108864.0   // 2^26 for (poscnt, negcnt) packing

typedef unsigned int uint32;
typedef unsigned short ushort16;

static __device__ __forceinline__ float bf2f(ushort16 u) {
    union { uint32 i; float f; } v; v.i = ((uint32)u) << 16; return v.f;
}
static __device__ __forceinline__ ushort16 f2bf(float f) {
    __hip_bfloat16 h = __float2bfloat16(f);  // RNE
    union { __hip_bfloat16 h; ushort16 u; } v; v.h = h; return v.u;
}

// ---------------- K0: detect input dtype (block 0) + zero accumulators ----------------
__global__ void detect_init_kernel(const uint32* __restrict__ rawA, int* __restrict__ flag,
                                   double* __restrict__ acc, double* __restrict__ gstats) {
    if (blockIdx.x == 0) {
        __shared__ int s_top2, s_nz;
        if (threadIdx.x == 0) { s_top2 = 0; s_nz = 0; }
        __syncthreads();
        int top2 = 0, nz = 0;
        for (int i = threadIdx.x; i < 4096; i += 256) {
            uint32 lo = rawA[i] & 0xFFFFu;
            if (lo & 0xC000u) top2 = 1;
            if (lo) nz = 1;
        }
        if (top2) atomicOr(&s_top2, 1);
        if (nz) atomicOr(&s_nz, 1);
        __syncthreads();
        if (threadIdx.x == 0) {
            int f;
            if (s_top2) f = 1;        // true fp32
            else if (s_nz) f = 0;     // bf16 storage
            else f = 1;               // fp32 holding bf16-rounded values
            *flag = f;
        }
    } else {
        int i = (blockIdx.x - 1) * 256 + threadIdx.x;
        if (i < 3 * NN) acc[i] = 0.0;
        if (i < 2) gstats[i] = 0.0;
    }
}

// ---------------- K1: top-32 mask + build X = [Ac | As] (fp32) + sq ----------------
__global__ void prep_kernel(const void* __restrict__ P_, const void* __restrict__ A_,
                            const int* __restrict__ flag,
                            float* __restrict__ X, float* __restrict__ sq) {
    int f = *flag;
    int row = blockIdx.x * 4 + (threadIdx.x >> 6);
    int lane = threadIdx.x & 63;
    if (row >= NN) return;
    float a[4], p[4];
    bool sel[4] = {false, false, false, false};
    if (f) {
        const float* Ar = (const float*)A_ + (size_t)row * KF;
        const float* Pr = (const float*)P_ + (size_t)row * KF;
#pragma unroll
        for (int j = 0; j < 4; j++) {
            int k = lane + 64 * j;
            a[j] = Ar[k];
            p[j] = Pr[k];
        }
    } else {
        const __hip_bfloat16* Ar = (const __hip_bfloat16*)A_ + (size_t)row * KF;
        const __hip_bfloat16* Pr = (const __hip_bfloat16*)P_ + (size_t)row * KF;
#pragma unroll
        for (int j = 0; j < 4; j++) {
            int k = lane + 64 * j;
            a[j] = __bfloat162float(Ar[k]);
            p[j] = __bfloat162float(Pr[k]);
        }
    }
    for (int it = 0; it < CK; ++it) {
        float bv = -1.0f; int bi = KF;
#pragma unroll
        for (int j = 0; j < 4; j++) {
            int k = lane + 64 * j;
            if (!sel[j] && (a[j] > bv || (a[j] == bv && k < bi))) { bv = a[j]; bi = k; }
        }
        for (int off = 32; off > 0; off >>= 1) {
            float ov = __shfl_xor(bv, off);
            int   oi = __shfl_xor(bi, off);
            if (ov > bv || (ov == bv && oi < bi)) { bv = ov; bi = oi; }
        }
        if ((bi & 63) == lane) sel[bi >> 6] = true;
    }
    double sq_part = 0.0;
    float* Xr = X + (size_t)row * KD;
#pragma unroll
    for (int j = 0; j < 4; j++) {
        int k = lane + 64 * j;
        float c = 0.0f, s = 0.0f;
        if (sel[j]) {
            c = a[j] * cosf(p[j]);
            s = a[j] * sinf(p[j]);
            sq_part += (double)a[j] * (double)a[j];
        }
        Xr[k] = c;
        Xr[KF + k] = s;
    }
    for (int off = 32; off > 0; off >>= 1) sq_part += __shfl_xor(sq_part, off);
    if (lane == 0) sq[row] = (float)sq_part;
}

// ---------------- K2: symmetric fp32 GEMM, dbuf LDS, 128x128 tile, 256 thr, TM8xTN8 ----------------
#define BM 128
#define BN 128
#define BK 8
#define TM 8
#define TN 8
#define LDP 140   // swizzled physical row length: sw(127)=139 -> 140

static __device__ __forceinline__ int sw(int c) { return c + ((c >> 5) << 2); }

__global__ __launch_bounds__(256)
void gemm_kernel(const float* __restrict__ X, const float* __restrict__ sq,
                 void* __restrict__ outv, const int* __restrict__ flag,
                 double* __restrict__ rowsum, double* __restrict__ possum,
                 double* __restrict__ pcnt) {
    int bx = blockIdx.x, by = blockIdx.y;
    if (bx < by) return;                    // upper-triangle tiles only
    __shared__ float As[2][BK][LDP];
    __shared__ float Bs[2][BK][LDP];
    int f = *flag;
    int tid = threadIdx.x;
    int tx = tid & 15;        // col group (TN=8)
    int ty = tid >> 4;        // row group (TM=8)
    int row0 = by * BM, col0 = bx * BN;

    float acc[TM][TN] = {};

    // staging: each thread loads one float4 of A-tile and one of B-tile per iter
    int lr = tid >> 1;            // 0..127
    int lk = (tid & 1) * 4;       // 0 or 4
    int slr = sw(lr);
    const float* Arow = X + (size_t)(row0 + lr) * KD + lk;
    const float* Brow = X + (size_t)(col0 + lr) * KD + lk;
    int sa0 = sw(ty * TM + 0), sa1 = sw(ty * TM + 4);
    int sb0 = sw(tx * TN + 0), sb1 = sw(tx * TN + 4);

#define STAGE(b, va, vb)                                                          \
    As[b][lk + 0][slr] = va.x; As[b][lk + 1][slr] = va.y;                         \
    As[b][lk + 2][slr] = va.z; As[b][lk + 3][slr] = va.w;                         \
    Bs[b][lk + 0][slr] = vb.x; Bs[b][lk + 1][slr] = vb.y;                         \
    Bs[b][lk + 2][slr] = vb.z; Bs[b][lk + 3][slr] = vb.w;

#define INNER(b)                                                                  \
    _Pragma("unroll")                                                             \
    for (int k = 0; k < BK; k++) {                                                \
        float4 va0 = *(const float4*)&As[b][k][sa0];                              \
        float4 va1 = *(const float4*)&As[b][k][sa1];                              \
        float4 vb0 = *(const float4*)&Bs[b][k][sb0];                              \
        float4 vb1 = *(const float4*)&Bs[b][k][sb1];                              \
        float av[TM] = {va0.x, va0.y, va0.z, va0.w, va1.x, va1.y, va1.z, va1.w};  \
        float bv[TN] = {vb0.x, vb0.y, vb0.z, vb0.w, vb1.x, vb1.y, vb1.z, vb1.w};  \
        _Pragma("unroll")                                                         \
        for (int i = 0; i < TM; i++)                                              \
            _Pragma("unroll")                                                     \
            for (int j = 0; j < TN; j++)                                          \
                acc[i][j] = fmaf(av[i], bv[j], acc[i][j]);                        \
    }

    // prologue: fill buffer 0
    {
        float4 pa = *(const float4*)(Arow);
        float4 pb = *(const float4*)(Brow);
        STAGE(0, pa, pb)
    }
    __syncthreads();
    // main loop, unrolled x2 for literal buffer indices; KD/BK = 64 iters
    for (int k0 = 0; k0 < KD; k0 += 2 * BK) {
        {   // iter A: compute buf0, prefetch+stage buf1 (k0+BK < KD always here)
            float4 na = *(const float4*)(Arow + k0 + BK);
            float4 nb = *(const float4*)(Brow + k0 + BK);
            INNER(0)
            STAGE(1, na, nb)
            __syncthreads();
        }
        {   // iter B: compute buf1, prefetch+stage buf0 unless last
            if (k0 + 2 * BK < KD) {
                float4 na = *(const float4*)(Arow + k0 + 2 * BK);
                float4 nb = *(const float4*)(Brow + k0 + 2 * BK);
                INNER(1)
                STAGE(0, na, nb)
                __syncthreads();
            } else {
                INNER(1)
            }
        }
    }

    // ---- epilogue: R = num/denom in-place, direct store, row stats ----
    float sqi[TM], sqj[TN];
#pragma unroll
    for (int i = 0; i < TM; i++) sqi[i] = sq[row0 + ty * TM + i];
#pragma unroll
    for (int j = 0; j < TN; j++) sqj[j] = sq[col0 + tx * TN + j];

#pragma unroll
    for (int i = 0; i < TM; i++) {
        double rs_ = 0.0, ps_ = 0.0;
        float pc_ = 0.0f, nc_ = 0.0f;
#pragma unroll
        for (int j = 0; j < TN; j++) {
            float denom = sqrtf(sqi[i] * sqj[j] + 1e-10f);
            float r = acc[i][j] / denom;        // IEEE div, matches np
            acc[i][j] = r;
            rs_ += (double)r;
            if (r > 0.0f) { ps_ += (double)r; pc_ += 1.0f; }
            else if (r < 0.0f) { nc_ += 1.0f; }
        }
        size_t obase = (((size_t)(row0 + ty * TM + i)) << 13) + col0 + tx * TN;
        if (f) {
            float* O = (float*)outv;
            *(float4*)(O + obase)     = make_float4(acc[i][0], acc[i][1], acc[i][2], acc[i][3]);
            *(float4*)(O + obase + 4) = make_float4(acc[i][4], acc[i][5], acc[i][6], acc[i][7]);
        } else {
            union { uint4 u; ushort16 s[8]; } pk;
#pragma unroll
            for (int j = 0; j < TN; j++) pk.s[j] = f2bf(acc[i][j]);
            *(uint4*)((__hip_bfloat16*)outv + obase) = pk.u;
        }
        // reduce across the 16 tx-threads (consecutive lanes within a wave)
        for (int off = 1; off < 16; off <<= 1) {
            rs_ += __shfl_xor(rs_, off);
            ps_ += __shfl_xor(ps_, off);
            pc_ += __shfl_xor(pc_, off);
            nc_ += __shfl_xor(nc_, off);
        }
        if (tx == 0) {
            int gr = row0 + ty * TM + i;
            atomicAdd(&rowsum[gr], rs_);
            atomicAdd(&possum[gr], ps_);
            atomicAdd(&pcnt[gr], (double)pc_ * PACK + (double)nc_);
        }
    }

    // ---- mirror tile (off-diagonal only): transposed store + column stats ----
    if (bx != by) {
        int l = tid & 63;
#pragma unroll
        for (int j = 0; j < TN; j++) {
            size_t mbase = (((size_t)(col0 + tx * TN + j)) << 13) + row0 + ty * TM;
            if (f) {
                float* O = (float*)outv;
                *(float4*)(O + mbase + 0) = make_float4(acc[0][j], acc[1][j], acc[2][j], acc[3][j]);
                *(float4*)(O + mbase + 4) = make_float4(acc[4][j], acc[5][j], acc[6][j], acc[7][j]);
            } else {
                union { uint4 u; ushort16 s[8]; } pk;
#pragma unroll
                for (int i = 0; i < 8; i++) pk.s[i] = f2bf(acc[i][j]);
                *(uint4*)((__hip_bfloat16*)outv + mbase) = pk.u;
            }
            double cs = 0.0, cp = 0.0;
            float cc = 0.0f, cn = 0.0f;
#pragma unroll
            for (int i = 0; i < TM; i++) {
                float r = acc[i][j];
                cs += (double)r;
                if (r > 0.0f) { cp += (double)r; cc += 1.0f; }
                else if (r < 0.0f) { cn += 1.0f; }
            }
            // reduce over the 4 ty-groups within this wave (lane bits 4,5)
            cs += __shfl_xor(cs, 16); cs += __shfl_xor(cs, 32);
            cp += __shfl_xor(cp, 16); cp += __shfl_xor(cp, 32);
            cc += __shfl_xor(cc, 16); cc += __shfl_xor(cc, 32);
            cn += __shfl_xor(cn, 16); cn += __shfl_xor(cn, 32);
            if (l < 16) {
                int gc = col0 + l * TN + j;    // tx == l for l < 16
                atomicAdd(&rowsum[gc], cs);
                atomicAdd(&possum[gc], cp);
                atomicAdd(&pcnt[gc], (double)cc * PACK + (double)cn);
            }
        }
    }
#undef STAGE
#undef INNER
}

// ---------------- K3: per-row finalize + global positive stats ----------------
__global__ void rowfin_kernel(const double* __restrict__ rowsum, const double* __restrict__ possum,
                              const double* __restrict__ pcnt,
                              float* __restrict__ inv_rs, double* __restrict__ gstats) {
    __shared__ double sc[256], sn[256];
    int n = blockIdx.x * 256 + threadIdx.x;
    double rsumv = rowsum[n];
    double rs = rsumv + 1e-10;
    inv_rs[n] = (float)(1.0 / rs);
    double packed = pcnt[n];
    double pc = floor(packed * (1.0 / PACK));
    double nc = packed - pc * PACK;
    double contrib, cnt;
    if (rs > 0.0) { contrib = possum[n] / rs; cnt = pc; }
    else          { contrib = (rsumv - possum[n]) / rs; cnt = nc; }
    sc[threadIdx.x] = contrib; sn[threadIdx.x] = cnt;
    __syncthreads();
    for (int s = 128; s > 0; s >>= 1) {
        if (threadIdx.x < s) { sc[threadIdx.x] += sc[threadIdx.x + s]; sn[threadIdx.x] += sn[threadIdx.x + s]; }
        __syncthreads();
    }
    if (threadIdx.x == 0) { atomicAdd(&gstats[0], sc[0]); atomicAdd(&gstats[1], sn[0]); }
}

// ---------------- K3b: tau ----------------
__global__ void tau_kernel(const double* __restrict__ gstats, float* __restrict__ tau) {
    double cnt = gstats[1];
    if (cnt < 1.0) cnt = 1.0;
    double mp = gstats[0] / cnt;
    tau[0] = (mp > 0.0) ? (float)mp : 1.0f;   // TAU_FACTOR = 1.0
}

// ---------------- K4: R' = R*inv_rs, threshold, in-place on d_out ----------------
__global__ void thresh_kernel(void* __restrict__ R_,
                              const float* __restrict__ inv_rs,
                              const float* __restrict__ tau_p,
                              const int* __restrict__ flag) {
    int f = *flag;
    float tau = *tau_p;
    size_t base = ((size_t)blockIdx.x * 256 + threadIdx.x) * 8;
    if (base >= (size_t)NN * NN) return;
    float inv = inv_rs[base >> 13];
    if (f) {
        float* R = (float*)R_;
        float4 v0 = *(float4*)(R + base);
        float4 v1 = *(float4*)(R + base + 4);
        float vv[8] = {v0.x, v0.y, v0.z, v0.w, v1.x, v1.y, v1.z, v1.w};
#pragma unroll
        for (int t = 0; t < 8; t++) {
            float val = vv[t] * inv;
            vv[t] = (val >= tau) ? val : 0.0f;
        }
        *(float4*)(R + base)     = make_float4(vv[0], vv[1], vv[2], vv[3]);
        *(float4*)(R + base + 4) = make_float4(vv[4], vv[5], vv[6], vv[7]);
    } else {
        __hip_bfloat16* R = (__hip_bfloat16*)R_;
        union { uint4 u; ushort16 s[8]; } in, out;
        in.u = *(const uint4*)(R + base);
#pragma unroll
        for (int t = 0; t < 8; t++) {
            float val = bf2f(in.s[t]) * inv;
            float r = (val >= tau) ? val : 0.0f;
            out.s[t] = f2bf(r);
        }
        *(uint4*)(R + base) = out.u;
    }
}

// ---------------- sentinel: ws too small -> unmistakable absmax signature ----------------
__global__ void sentinel_kernel(uint32* __restrict__ out, size_t n32) {
    size_t i = (size_t)blockIdx.x * 256 + threadIdx.x;
    if (i < n32) out[i] = 0x47C35000u;
}

extern "C" void kernel_launch(void* const* d_in, const int* in_sizes, int n_in,
                              void* d_out, int out_size, void* d_ws, size_t ws_size,
                              hipStream_t stream) {
    const void* P = d_in[0];
    const void* A = d_in[1];

    char* ws = (char*)d_ws;
    size_t off = 0;
    float* X = (float*)(ws + off);        off += (size_t)NN * KD * 4;   // 16 MB
    float* sqv = (float*)(ws + off);      off += (size_t)NN * 4;
    double* rowsum = (double*)(ws + off); off += (size_t)NN * 8;
    double* possum = (double*)(ws + off); off += (size_t)NN * 8;
    double* pcnt = (double*)(ws + off);   off += (size_t)NN * 8;
    float* inv_rs = (float*)(ws + off);   off += (size_t)NN * 4;
    double* gstats = (double*)(ws + off); off += 16;
    float* tau = (float*)(ws + off);      off += 16;
    int* flag = (int*)(ws + off);         off += 16;

    if (ws_size < off) {
        size_t n32 = ((size_t)out_size * 2) / 4;
        sentinel_kernel<<<(int)((n32 + 255) / 256), 256, 0, stream>>>((uint32*)d_out, n32);
        return;
    }

    detect_init_kernel<<<1 + (3 * NN + 255) / 256, 256, 0, stream>>>((const uint32*)A, flag, rowsum, gstats);
    prep_kernel<<<NN / 4, 256, 0, stream>>>(P, A, flag, X, sqv);
    dim3 ggrid(NN / BN, NN / BM);
    gemm_kernel<<<ggrid, 256, 0, stream>>>(X, sqv, d_out, flag, rowsum, possum, pcnt);
    rowfin_kernel<<<NN / 256, 256, 0, stream>>>(rowsum, possum, pcnt, inv_rs, gstats);
    tau_kernel<<<1, 1, 0, stream>>>(gstats, tau);
    thresh_kernel<<<(int)(((size_t)NN * NN / 8 + 255) / 256), 256, 0, stream>>>(d_out, inv_rs, tau, flag);
}

// Round 7
// 1014.674 us; speedup vs baseline: 1.3340x; 1.0512x over previous
//
#include <hip/hip_runtime.h>
#include <hip/hip_bf16.h>

#define NN 8192
#define KF 256
#define KD 512
#define CK 32
#define PACK 67108864.0   // 2^26 for (poscnt, negcnt) packing

typedef unsigned int uint32;
typedef unsigned short ushort16;
typedef __attribute__((ext_vector_type(8))) short bf16x8;
typedef __attribute__((ext_vector_type(4))) float f32x4;

static __device__ __forceinline__ float bf2f(ushort16 u) {
    union { uint32 i; float f; } v; v.i = ((uint32)u) << 16; return v.f;
}
static __device__ __forceinline__ ushort16 f2bf(float f) {
    __hip_bfloat16 h = __float2bfloat16(f);  // RNE
    union { __hip_bfloat16 h; ushort16 u; } v; v.h = h; return v.u;
}
// exact 3-way bf16 split: x = h + l + l2 + O(2^-26 x)
static __device__ __forceinline__ void split3(float x, ushort16& h, ushort16& l, ushort16& l2) {
    h = f2bf(x);
    float r1 = x - bf2f(h);
    l = f2bf(r1);
    float r2 = r1 - bf2f(l);
    l2 = f2bf(r2);
}

// ---------------- K0: detect input dtype (block 0) + zero accumulators ----------------
__global__ void detect_init_kernel(const uint32* __restrict__ rawA, int* __restrict__ flag,
                                   double* __restrict__ acc, double* __restrict__ gstats) {
    if (blockIdx.x == 0) {
        __shared__ int s_top2, s_nz;
        if (threadIdx.x == 0) { s_top2 = 0; s_nz = 0; }
        __syncthreads();
        int top2 = 0, nz = 0;
        for (int i = threadIdx.x; i < 4096; i += 256) {
            uint32 lo = rawA[i] & 0xFFFFu;
            if (lo & 0xC000u) top2 = 1;
            if (lo) nz = 1;
        }
        if (top2) atomicOr(&s_top2, 1);
        if (nz) atomicOr(&s_nz, 1);
        __syncthreads();
        if (threadIdx.x == 0) {
            int f;
            if (s_top2) f = 1;        // true fp32
            else if (s_nz) f = 0;     // bf16 storage
            else f = 1;               // fp32 holding bf16-rounded values
            *flag = f;
        }
    } else {
        int i = (blockIdx.x - 1) * 256 + threadIdx.x;
        if (i < 3 * NN) acc[i] = 0.0;
        if (i < 2) gstats[i] = 0.0;
    }
}

// ---------------- K1: top-32 mask + build split matrices Xh/Xl/Xl2 (bf16) + sq ----------------
__global__ void prep_kernel(const void* __restrict__ P_, const void* __restrict__ A_,
                            const int* __restrict__ flag,
                            ushort16* __restrict__ Xh, ushort16* __restrict__ Xl,
                            ushort16* __restrict__ Xl2, float* __restrict__ sq) {
    int f = *flag;
    int row = blockIdx.x * 4 + (threadIdx.x >> 6);
    int lane = threadIdx.x & 63;
    if (row >= NN) return;
    float a[4], p[4];
    bool sel[4] = {false, false, false, false};
    if (f) {
        const float* Ar = (const float*)A_ + (size_t)row * KF;
        const float* Pr = (const float*)P_ + (size_t)row * KF;
#pragma unroll
        for (int j = 0; j < 4; j++) {
            int k = lane + 64 * j;
            a[j] = Ar[k];
            p[j] = Pr[k];
        }
    } else {
        const __hip_bfloat16* Ar = (const __hip_bfloat16*)A_ + (size_t)row * KF;
        const __hip_bfloat16* Pr = (const __hip_bfloat16*)P_ + (size_t)row * KF;
#pragma unroll
        for (int j = 0; j < 4; j++) {
            int k = lane + 64 * j;
            a[j] = __bfloat162float(Ar[k]);
            p[j] = __bfloat162float(Pr[k]);
        }
    }
    for (int it = 0; it < CK; ++it) {
        float bv = -1.0f; int bi = KF;
#pragma unroll
        for (int j = 0; j < 4; j++) {
            int k = lane + 64 * j;
            if (!sel[j] && (a[j] > bv || (a[j] == bv && k < bi))) { bv = a[j]; bi = k; }
        }
        for (int off = 32; off > 0; off >>= 1) {
            float ov = __shfl_xor(bv, off);
            int   oi = __shfl_xor(bi, off);
            if (ov > bv || (ov == bv && oi < bi)) { bv = ov; bi = oi; }
        }
        if ((bi & 63) == lane) sel[bi >> 6] = true;
    }
    double sq_part = 0.0;
    size_t rb = (size_t)row * KD;
#pragma unroll
    for (int j = 0; j < 4; j++) {
        int k = lane + 64 * j;
        float c = 0.0f, s = 0.0f;
        if (sel[j]) {
            c = a[j] * cosf(p[j]);
            s = a[j] * sinf(p[j]);
            sq_part += (double)a[j] * (double)a[j];
        }
        ushort16 h, l, l2;
        split3(c, h, l, l2);
        Xh[rb + k] = h; Xl[rb + k] = l; Xl2[rb + k] = l2;
        split3(s, h, l, l2);
        Xh[rb + KF + k] = h; Xl[rb + KF + k] = l; Xl2[rb + KF + k] = l2;
    }
    for (int off = 32; off > 0; off >>= 1) sq_part += __shfl_xor(sq_part, off);
    if (lane == 0) sq[row] = (float)sq_part;
}

// ---------------- K2: symmetric bf16x3 MFMA GEMM, 128x128 tile, 256 thr ----------------
// LDS: 6 regions (Ah,Al,Al2,Bh,Bl,Bl2) x 128 rows x 32 bf16, quad-swizzled.
#define MM(A, B)                                                                   \
    _Pragma("unroll") for (int tm = 0; tm < 4; tm++)                               \
    _Pragma("unroll") for (int tn = 0; tn < 4; tn++)                               \
        acc[tm][tn] = __builtin_amdgcn_mfma_f32_16x16x32_bf16(A[tm], B[tn], acc[tm][tn], 0, 0, 0);

#define LOADF(dst, region, wbase)                                                  \
    _Pragma("unroll") for (int t = 0; t < 4; t++)                                  \
        dst[t] = *(const bf16x8*)&lds4[(region)*512 + ((wbase) + t*16 + r15)*4 + qp];

__global__ __launch_bounds__(256)
void gemm_kernel(const ushort16* __restrict__ Xh, const ushort16* __restrict__ Xl,
                 const ushort16* __restrict__ Xl2, const float* __restrict__ sq,
                 void* __restrict__ outv, const int* __restrict__ flag,
                 double* __restrict__ rowsum, double* __restrict__ possum,
                 double* __restrict__ pcnt) {
    int bx = blockIdx.x, by = blockIdx.y;
    if (bx < by) return;                    // upper-triangle tiles only
    __shared__ uint4 lds4[3072];            // 48 KB
    int f = *flag;
    int tid = threadIdx.x;
    int wave = tid >> 6;
    int wm = wave >> 1, wn = wave & 1;      // 2x2 wave grid of 64x64 blocks
    int L = tid & 63, quad = L >> 4, r15 = L & 15;
    int qp = quad ^ (r15 & 3);              // swizzled quad slot
    int row0 = by * 128, col0 = bx * 128;

    f32x4 acc[4][4];
#pragma unroll
    for (int tm = 0; tm < 4; tm++)
#pragma unroll
        for (int tn = 0; tn < 4; tn++) acc[tm][tn] = (f32x4){0.f, 0.f, 0.f, 0.f};

    // staging slots: thread handles slot tid and 256+tid (512 slots = 128 rows x 4 quads)
    int s0 = tid, s1 = 256 + tid;
    int r0 = s0 >> 2, q0 = (s0 & 3) ^ (r0 & 3);
    int r1 = s1 >> 2, q1 = (s1 & 3) ^ (r1 & 3);
    const ushort16* pAh0 = Xh  + (size_t)(row0 + r0) * KD + q0 * 8;
    const ushort16* pAh1 = Xh  + (size_t)(row0 + r1) * KD + q1 * 8;
    const ushort16* pAl0 = Xl  + (size_t)(row0 + r0) * KD + q0 * 8;
    const ushort16* pAl1 = Xl  + (size_t)(row0 + r1) * KD + q1 * 8;
    const ushort16* pAm0 = Xl2 + (size_t)(row0 + r0) * KD + q0 * 8;
    const ushort16* pAm1 = Xl2 + (size_t)(row0 + r1) * KD + q1 * 8;
    const ushort16* pBh0 = Xh  + (size_t)(col0 + r0) * KD + q0 * 8;
    const ushort16* pBh1 = Xh  + (size_t)(col0 + r1) * KD + q1 * 8;
    const ushort16* pBl0 = Xl  + (size_t)(col0 + r0) * KD + q0 * 8;
    const ushort16* pBl1 = Xl  + (size_t)(col0 + r1) * KD + q1 * 8;
    const ushort16* pBm0 = Xl2 + (size_t)(col0 + r0) * KD + q0 * 8;
    const ushort16* pBm1 = Xl2 + (size_t)(col0 + r1) * KD + q1 * 8;

    for (int k0 = 0; k0 < KD; k0 += 32) {
        uint4 v0  = *(const uint4*)(pAh0 + k0), v1  = *(const uint4*)(pAh1 + k0);
        uint4 v2  = *(const uint4*)(pAl0 + k0), v3  = *(const uint4*)(pAl1 + k0);
        uint4 v4  = *(const uint4*)(pAm0 + k0), v5  = *(const uint4*)(pAm1 + k0);
        uint4 v6  = *(const uint4*)(pBh0 + k0), v7  = *(const uint4*)(pBh1 + k0);
        uint4 v8  = *(const uint4*)(pBl0 + k0), v9  = *(const uint4*)(pBl1 + k0);
        uint4 v10 = *(const uint4*)(pBm0 + k0), v11 = *(const uint4*)(pBm1 + k0);
        __syncthreads();
        lds4[0 * 512 + s0] = v0;  lds4[0 * 512 + s1] = v1;
        lds4[1 * 512 + s0] = v2;  lds4[1 * 512 + s1] = v3;
        lds4[2 * 512 + s0] = v4;  lds4[2 * 512 + s1] = v5;
        lds4[3 * 512 + s0] = v6;  lds4[3 * 512 + s1] = v7;
        lds4[4 * 512 + s0] = v8;  lds4[4 * 512 + s1] = v9;
        lds4[5 * 512 + s0] = v10; lds4[5 * 512 + s1] = v11;
        __syncthreads();

        bf16x8 fa[4], fb[4], ga[4], gb[4];
        LOADF(fa, 0, wm * 64)      // Ah
        LOADF(fb, 3, wn * 64)      // Bh
        MM(fa, fb)                 // h*h
        LOADF(gb, 4, wn * 64)      // Bl
        MM(fa, gb)                 // h*l
        LOADF(ga, 1, wm * 64)      // Al
        MM(ga, fb)                 // l*h
        MM(ga, gb)                 // l*l
        LOADF(gb, 5, wn * 64)      // Bl2 (overwrite)
        MM(fa, gb)                 // h*l2
        LOADF(ga, 2, wm * 64)      // Al2 (overwrite)
        MM(ga, fb)                 // l2*h
    }

    // ---- epilogue: R = num/denom in registers (C-layout: row=quad*4+g, col=r15) ----
    float sqj[4], sqiv[4][4];
#pragma unroll
    for (int tn = 0; tn < 4; tn++) sqj[tn] = sq[col0 + wn * 64 + tn * 16 + r15];
#pragma unroll
    for (int tm = 0; tm < 4; tm++)
#pragma unroll
        for (int g = 0; g < 4; g++) sqiv[tm][g] = sq[row0 + wm * 64 + tm * 16 + quad * 4 + g];
#pragma unroll
    for (int tm = 0; tm < 4; tm++)
#pragma unroll
        for (int tn = 0; tn < 4; tn++)
#pragma unroll
            for (int g = 0; g < 4; g++) {
                float denom = sqrtf(sqiv[tm][g] * sqj[tn] + 1e-10f);
                acc[tm][tn][g] = acc[tm][tn][g] / denom;   // IEEE div, matches np
            }

    // ---- row stats (direct tile) ----
#pragma unroll
    for (int tm = 0; tm < 4; tm++)
#pragma unroll
        for (int g = 0; g < 4; g++) {
            double rs_ = 0.0, ps_ = 0.0;
            float pc_ = 0.0f, nc_ = 0.0f;
#pragma unroll
            for (int tn = 0; tn < 4; tn++) {
                float r = acc[tm][tn][g];
                rs_ += (double)r;
                if (r > 0.0f) { ps_ += (double)r; pc_ += 1.0f; }
                else if (r < 0.0f) { nc_ += 1.0f; }
            }
            for (int off = 1; off < 16; off <<= 1) {
                rs_ += __shfl_xor(rs_, off);
                ps_ += __shfl_xor(ps_, off);
                pc_ += __shfl_xor(pc_, off);
                nc_ += __shfl_xor(nc_, off);
            }
            if (r15 == 0) {
                int gr = row0 + wm * 64 + tm * 16 + quad * 4 + g;
                atomicAdd(&rowsum[gr], rs_);
                atomicAdd(&possum[gr], ps_);
                atomicAdd(&pcnt[gr], (double)pc_ * PACK + (double)nc_);
            }
        }

    // ---- mirror tile + column stats (off-diagonal only) ----
    if (bx != by) {
#pragma unroll
        for (int tm = 0; tm < 4; tm++)
#pragma unroll
            for (int tn = 0; tn < 4; tn++) {
                size_t mb = (((size_t)(col0 + wn * 64 + tn * 16 + r15)) << 13)
                            + row0 + wm * 64 + tm * 16 + quad * 4;
                if (f) {
                    *(float4*)((float*)outv + mb) =
                        make_float4(acc[tm][tn][0], acc[tm][tn][1], acc[tm][tn][2], acc[tm][tn][3]);
                } else {
                    union { uint2 u; ushort16 s[4]; } m;
#pragma unroll
                    for (int g = 0; g < 4; g++) m.s[g] = f2bf(acc[tm][tn][g]);
                    *(uint2*)((__hip_bfloat16*)outv + mb) = m.u;
                }
            }
#pragma unroll
        for (int tn = 0; tn < 4; tn++) {
            double cs = 0.0, cp = 0.0;
            float cc = 0.0f, cn = 0.0f;
#pragma unroll
            for (int tm = 0; tm < 4; tm++)
#pragma unroll
                for (int g = 0; g < 4; g++) {
                    float r = acc[tm][tn][g];
                    cs += (double)r;
                    if (r > 0.0f) { cp += (double)r; cc += 1.0f; }
                    else if (r < 0.0f) { cn += 1.0f; }
                }
            cs += __shfl_xor(cs, 16); cs += __shfl_xor(cs, 32);
            cp += __shfl_xor(cp, 16); cp += __shfl_xor(cp, 32);
            cc += __shfl_xor(cc, 16); cc += __shfl_xor(cc, 32);
            cn += __shfl_xor(cn, 16); cn += __shfl_xor(cn, 32);
            if (L < 16) {
                int gc = col0 + wn * 64 + tn * 16 + L;
                atomicAdd(&rowsum[gc], cs);
                atomicAdd(&possum[gc], cp);
                atomicAdd(&pcnt[gc], (double)cc * PACK + (double)cn);
            }
        }
    }

    // ---- direct store via per-wave LDS transpose (16-row stripes) ----
    __syncthreads();                        // k-loop frag reads fully done
    float* W = (float*)(lds4 + wave * 256); // private 4 KB per wave: 16 x 64 fp32
    int rr = L >> 2, cc2 = L & 3;
#pragma unroll
    for (int tm = 0; tm < 4; tm++) {
#pragma unroll
        for (int tn = 0; tn < 4; tn++)
#pragma unroll
            for (int g = 0; g < 4; g++) {
                int nibS = tn * 4 + (((r15 >> 2) ^ g) & 3);
                W[(quad * 4 + g) * 64 + nibS * 4 + (r15 & 3)] = acc[tm][tn][g];
            }
        float vals[16];
#pragma unroll
        for (int j = 0; j < 4; j++) {
            int nibS = cc2 * 4 + ((j ^ (rr & 3)) & 3);
            float4 fv = *(const float4*)&W[rr * 64 + nibS * 4];
            vals[j * 4 + 0] = fv.x; vals[j * 4 + 1] = fv.y;
            vals[j * 4 + 2] = fv.z; vals[j * 4 + 3] = fv.w;
        }
        int gr = row0 + wm * 64 + tm * 16 + rr;
        size_t ob = ((size_t)gr << 13) + col0 + wn * 64 + cc2 * 16;
        if (f) {
            float* O = (float*)outv;
#pragma unroll
            for (int j = 0; j < 4; j++)
                *(float4*)(O + ob + j * 4) =
                    make_float4(vals[j * 4], vals[j * 4 + 1], vals[j * 4 + 2], vals[j * 4 + 3]);
        } else {
            union { uint4 u; ushort16 s[8]; } p0, p1;
#pragma unroll
            for (int j = 0; j < 8; j++) p0.s[j] = f2bf(vals[j]);
#pragma unroll
            for (int j = 0; j < 8; j++) p1.s[j] = f2bf(vals[8 + j]);
            *(uint4*)((__hip_bfloat16*)outv + ob) = p0.u;
            *(uint4*)((__hip_bfloat16*)outv + ob + 8) = p1.u;
        }
        __syncthreads();   // cheap stripe fence: waves advance together, W reuse safe
    }
}

// ---------------- K3: per-row finalize + global positive stats ----------------
__global__ void rowfin_kernel(const double* __restrict__ rowsum, const double* __restrict__ possum,
                              const double* __restrict__ pcnt,
                              float* __restrict__ inv_rs, double* __restrict__ gstats) {
    __shared__ double sc[256], sn[256];
    int n = blockIdx.x * 256 + threadIdx.x;
    double rsumv = rowsum[n];
    double rs = rsumv + 1e-10;
    inv_rs[n] = (float)(1.0 / rs);
    double packed = pcnt[n];
    double pc = floor(packed * (1.0 / PACK));
    double nc = packed - pc * PACK;
    double contrib, cnt;
    if (rs > 0.0) { contrib = possum[n] / rs; cnt = pc; }
    else          { contrib = (rsumv - possum[n]) / rs; cnt = nc; }
    sc[threadIdx.x] = contrib; sn[threadIdx.x] = cnt;
    __syncthreads();
    for (int s = 128; s > 0; s >>= 1) {
        if (threadIdx.x < s) { sc[threadIdx.x] += sc[threadIdx.x + s]; sn[threadIdx.x] += sn[threadIdx.x + s]; }
        __syncthreads();
    }
    if (threadIdx.x == 0) { atomicAdd(&gstats[0], sc[0]); atomicAdd(&gstats[1], sn[0]); }
}

// ---------------- K3b: tau ----------------
__global__ void tau_kernel(const double* __restrict__ gstats, float* __restrict__ tau) {
    double cnt = gstats[1];
    if (cnt < 1.0) cnt = 1.0;
    double mp = gstats[0] / cnt;
    tau[0] = (mp > 0.0) ? (float)mp : 1.0f;   // TAU_FACTOR = 1.0
}

// ---------------- K4: R' = R*inv_rs, threshold, in-place on d_out ----------------
__global__ void thresh_kernel(void* __restrict__ R_,
                              const float* __restrict__ inv_rs,
                              const float* __restrict__ tau_p,
                              const int* __restrict__ flag) {
    int f = *flag;
    float tau = *tau_p;
    size_t base = ((size_t)blockIdx.x * 256 + threadIdx.x) * 8;
    if (base >= (size_t)NN * NN) return;
    float inv = inv_rs[base >> 13];
    if (f) {
        float* R = (float*)R_;
        float4 v0 = *(float4*)(R + base);
        float4 v1 = *(float4*)(R + base + 4);
        float vv[8] = {v0.x, v0.y, v0.z, v0.w, v1.x, v1.y, v1.z, v1.w};
#pragma unroll
        for (int t = 0; t < 8; t++) {
            float val = vv[t] * inv;
            vv[t] = (val >= tau) ? val : 0.0f;
        }
        *(float4*)(R + base)     = make_float4(vv[0], vv[1], vv[2], vv[3]);
        *(float4*)(R + base + 4) = make_float4(vv[4], vv[5], vv[6], vv[7]);
    } else {
        __hip_bfloat16* R = (__hip_bfloat16*)R_;
        union { uint4 u; ushort16 s[8]; } in, out;
        in.u = *(const uint4*)(R + base);
#pragma unroll
        for (int t = 0; t < 8; t++) {
            float val = bf2f(in.s[t]) * inv;
            float r = (val >= tau) ? val : 0.0f;
            out.s[t] = f2bf(r);
        }
        *(uint4*)(R + base) = out.u;
    }
}

// ---------------- sentinel: ws too small -> unmistakable absmax signature ----------------
__global__ void sentinel_kernel(uint32* __restrict__ out, size_t n32) {
    size_t i = (size_t)blockIdx.x * 256 + threadIdx.x;
    if (i < n32) out[i] = 0x47C35000u;
}

extern "C" void kernel_launch(void* const* d_in, const int* in_sizes, int n_in,
                              void* d_out, int out_size, void* d_ws, size_t ws_size,
                              hipStream_t stream) {
    const void* P = d_in[0];
    const void* A = d_in[1];

    char* ws = (char*)d_ws;
    size_t off = 0;
    ushort16* Xh = (ushort16*)(ws + off);   off += (size_t)NN * KD * 2;   // 8 MB
    ushort16* Xl = (ushort16*)(ws + off);   off += (size_t)NN * KD * 2;   // 8 MB
    ushort16* Xl2 = (ushort16*)(ws + off);  off += (size_t)NN * KD * 2;   // 8 MB
    float* sqv = (float*)(ws + off);        off += (size_t)NN * 4;
    double* rowsum = (double*)(ws + off);   off += (size_t)NN * 8;
    double* possum = (double*)(ws + off);   off += (size_t)NN * 8;
    double* pcnt = (double*)(ws + off);     off += (size_t)NN * 8;
    float* inv_rs = (float*)(ws + off);     off += (size_t)NN * 4;
    double* gstats = (double*)(ws + off);   off += 16;
    float* tau = (float*)(ws + off);        off += 16;
    int* flag = (int*)(ws + off);           off += 16;

    if (ws_size < off) {
        size_t n32 = ((size_t)out_size * 2) / 4;
        sentinel_kernel<<<(int)((n32 + 255) / 256), 256, 0, stream>>>((uint32*)d_out, n32);
        return;
    }

    detect_init_kernel<<<1 + (3 * NN + 255) / 256, 256, 0, stream>>>((const uint32*)A, flag, rowsum, gstats);
    prep_kernel<<<NN / 4, 256, 0, stream>>>(P, A, flag, Xh, Xl, Xl2, sqv);
    dim3 ggrid(64, 64);
    gemm_kernel<<<ggrid, 256, 0, stream>>>(Xh, Xl, Xl2, sqv, d_out, flag, rowsum, possum, pcnt);
    rowfin_kernel<<<NN / 256, 256, 0, stream>>>(rowsum, possum, pcnt, inv_rs, gstats);
    tau_kernel<<<1, 1, 0, stream>>>(gstats, tau);
    thresh_kernel<<<(int)(((size_t)NN * NN / 8 + 255) / 256), 256, 0, stream>>>(d_out, inv_rs, tau, flag);
}